// Round 7
// baseline (539.508 us; speedup 1.0000x reference)
//
#include <hip/hip_runtime.h>
#include <math.h>

#define NNODES 50000
#define E0 800000
#define ETOT 850000
#define IN_DIM 1024
#define HEADS 4
#define C1 256      // HEADS*HID
#define C2 128      // OUT_DIM
#define NEG_SLOPE 0.2f

typedef short bf16x8 __attribute__((ext_vector_type(8)));
typedef float f32x4 __attribute__((ext_vector_type(4)));
typedef unsigned short ushort_t;

// ---------- helpers ----------
// NOTE: harness delivers integer inputs as int32 (verified round 1: int* passed,
// long long* faulted). Do NOT read edge_index as int64.
__device__ __forceinline__ void edge_sd(const int* __restrict__ ei, int e, int& s, int& d) {
    if (e < E0) { s = ei[e]; d = ei[E0 + e]; }
    else        { s = e - E0; d = s; }
}

__device__ __forceinline__ ushort_t f2b(float f) {   // f32 -> bf16 RNE
    unsigned u = __float_as_uint(f);
    return (ushort_t)((u + 0x7fffu + ((u >> 16) & 1u)) >> 16);
}
__device__ __forceinline__ float bf2f(ushort_t u) {
    return __uint_as_float((unsigned)u << 16);
}
__device__ __forceinline__ float lrelu(float v) { return v > 0.f ? v : NEG_SLOPE * v; }

__device__ __forceinline__ void gload_lds16(const void* g, void* l) {
    __builtin_amdgcn_global_load_lds(
        (const __attribute__((address_space(1))) unsigned int*)g,
        (__attribute__((address_space(3))) unsigned int*)l, 16, 0, 0);
}

// ---------- weight transpose + bf16 cast: W[K][N] f32 -> WT[N][K] bf16 ----------
__global__ __launch_bounds__(256) void wtrans_kernel(const float* __restrict__ W,
                                                     ushort_t* __restrict__ WT,
                                                     int K, int N)
{
    int idx = blockIdx.x * 256 + threadIdx.x;
    if (idx >= K * N) return;
    int k = idx / N, n = idx % N;
    WT[(size_t)n * K + k] = f2b(W[idx]);
}

// ---------- MFMA GEMM (A f32, cast in regs): Cb bf16 = A[M][K] @ Bt[N][K] ----------
// 128x128 tile, BK=32, 4 waves, DOUBLE-BUFFERED 2-phase pipeline:
//   STAGE(t+1 -> buf^1) issued BEFORE compute(buf); one barrier per K-step.
// LDS per buffer: [kchunk(4)][row(128)][8] bf16.
__global__ __launch_bounds__(256, 3) void gemm_fb(const float* __restrict__ A,
                                                  const ushort_t* __restrict__ Bt,
                                                  ushort_t* __restrict__ Cb,
                                                  int M, int N, int K)
{
    __shared__ __align__(16) ushort_t As[2][4 * 128 * 8];   // 2 x 8 KB
    __shared__ __align__(16) ushort_t Bs[2][4 * 128 * 8];   // 2 x 8 KB

    const int tid  = threadIdx.x;
    const int lane = tid & 63;
    const int wid  = tid >> 6;
    const int wr   = wid >> 1, wc = wid & 1;
    const int rowBase = blockIdx.y * 128;
    const int colBase = blockIdx.x * 128;

    // A staging (reg path): thread t covers row=t>>1, 16 k-values at (t&1)*16
    const int arow = tid >> 1;
    const int akh  = (tid & 1) * 2;
    const int aGRow = min(rowBase + arow, M - 1);
    const float* aptr = A + (size_t)aGRow * K + akh * 8;
    const int awoff0 = akh * 1024 + arow * 8;
    const int awoff1 = awoff0 + 1024;

    // B staging via global_load_lds: wave w stages kchunk plane w, halves c=0/1
    const ushort_t* bptr = Bt + (size_t)(colBase + lane) * K + wid * 8;
    const int bwoff0 = wid * 1024;       // wave-uniform LDS base (+lane*16 by HW)
    const int bwoff1 = bwoff0 + 512;

    const int r0 = lane & 15;
    const int kh = lane >> 4;
    const int ardoff = kh * 1024 + (wr * 64 + r0) * 8;
    const int brdoff = kh * 1024 + (wc * 64 + r0) * 8;

    f32x4 zero = {0.f, 0.f, 0.f, 0.f};
    f32x4 acc[4][4];
    #pragma unroll
    for (int i = 0; i < 4; ++i)
        #pragma unroll
        for (int j = 0; j < 4; ++j) acc[i][j] = zero;

    // ---- prologue: stage tile 0 into buffer 0 ----
    {
        float4 f0 = *(const float4*)(aptr + 0);
        float4 f1 = *(const float4*)(aptr + 4);
        float4 f2 = *(const float4*)(aptr + 8);
        float4 f3 = *(const float4*)(aptr + 12);
        bf16x8 p0, p1;
        p0[0] = f2b(f0.x); p0[1] = f2b(f0.y); p0[2] = f2b(f0.z); p0[3] = f2b(f0.w);
        p0[4] = f2b(f1.x); p0[5] = f2b(f1.y); p0[6] = f2b(f1.z); p0[7] = f2b(f1.w);
        p1[0] = f2b(f2.x); p1[1] = f2b(f2.y); p1[2] = f2b(f2.z); p1[3] = f2b(f2.w);
        p1[4] = f2b(f3.x); p1[5] = f2b(f3.y); p1[6] = f2b(f3.z); p1[7] = f2b(f3.w);
        *(bf16x8*)&As[0][awoff0] = p0;
        *(bf16x8*)&As[0][awoff1] = p1;
        gload_lds16(bptr, &Bs[0][bwoff0]);
        gload_lds16(bptr + (size_t)64 * K, &Bs[0][bwoff1]);
    }
    __syncthreads();   // vmcnt(0)+lgkmcnt(0) drain: tile 0 resident

    const ushort_t* rdA = As[0]; const ushort_t* rdB = Bs[0];
    ushort_t*       stA = As[1]; ushort_t*       stB = Bs[1];

    const int nt = K >> 5;
    for (int t = 0; t < nt; ++t) {
        const int kt = (t + 1) << 5;
        const bool has_next = kt < K;
        float4 f0, f1, f2, f3;
        if (has_next) {
            // issue next-tile loads BEFORE compute: latency hides under MFMA
            gload_lds16(bptr + kt, stB + bwoff0);
            gload_lds16(bptr + (size_t)64 * K + kt, stB + bwoff1);
            f0 = *(const float4*)(aptr + kt + 0);
            f1 = *(const float4*)(aptr + kt + 4);
            f2 = *(const float4*)(aptr + kt + 8);
            f3 = *(const float4*)(aptr + kt + 12);
        }

        bf16x8 af[4], bfr[4];
        #pragma unroll
        for (int fi = 0; fi < 4; ++fi) af[fi] = *(const bf16x8*)(rdA + ardoff + fi * 128);
        #pragma unroll
        for (int fj = 0; fj < 4; ++fj) bfr[fj] = *(const bf16x8*)(rdB + brdoff + fj * 128);
        #pragma unroll
        for (int fi = 0; fi < 4; ++fi)
            #pragma unroll
            for (int fj = 0; fj < 4; ++fj)
                acc[fi][fj] = __builtin_amdgcn_mfma_f32_16x16x32_bf16(
                    af[fi], bfr[fj], acc[fi][fj], 0, 0, 0);

        if (has_next) {
            bf16x8 p0, p1;
            p0[0] = f2b(f0.x); p0[1] = f2b(f0.y); p0[2] = f2b(f0.z); p0[3] = f2b(f0.w);
            p0[4] = f2b(f1.x); p0[5] = f2b(f1.y); p0[6] = f2b(f1.z); p0[7] = f2b(f1.w);
            p1[0] = f2b(f2.x); p1[1] = f2b(f2.y); p1[2] = f2b(f2.z); p1[3] = f2b(f2.w);
            p1[4] = f2b(f3.x); p1[5] = f2b(f3.y); p1[6] = f2b(f3.z); p1[7] = f2b(f3.w);
            *(bf16x8*)(stA + awoff0) = p0;
            *(bf16x8*)(stA + awoff1) = p1;
        }
        __syncthreads();   // publishes buf^1 (drains B gload_lds + A ds_write)
        const ushort_t* tA = rdA; rdA = stA; stA = (ushort_t*)tA;
        const ushort_t* tB = rdB; rdB = stB; stB = (ushort_t*)tB;
    }

    // C/D layout (m89-verified): col = lane&15, row = (lane>>4)*4 + reg
    #pragma unroll
    for (int fi = 0; fi < 4; ++fi) {
        int row0 = rowBase + wr * 64 + fi * 16 + kh * 4;
        #pragma unroll
        for (int i = 0; i < 4; ++i) {
            int row = row0 + i;
            if (row < M) {
                #pragma unroll
                for (int fj = 0; fj < 4; ++fj)
                    Cb[(size_t)row * N + colBase + wc * 64 + fj * 16 + r0] = f2b(acc[fi][fj][i]);
            }
        }
    }
}

// ---------- MFMA GEMM (A bf16 direct): same double-buffered 2-phase pipeline ----------
__global__ __launch_bounds__(256, 4) void gemm_bb(const ushort_t* __restrict__ Ab,
                                                  const ushort_t* __restrict__ Bt,
                                                  ushort_t* __restrict__ Cb,
                                                  int M, int N, int K)
{
    __shared__ __align__(16) ushort_t As[2][4 * 128 * 8];
    __shared__ __align__(16) ushort_t Bs[2][4 * 128 * 8];

    const int tid  = threadIdx.x;
    const int lane = tid & 63;
    const int wid  = tid >> 6;
    const int wr   = wid >> 1, wc = wid & 1;
    const int rowBase = blockIdx.y * 128;
    const int colBase = blockIdx.x * 128;

    const ushort_t* aptr0 = Ab + (size_t)min(rowBase + lane, M - 1) * K + wid * 8;
    const ushort_t* aptr1 = Ab + (size_t)min(rowBase + 64 + lane, M - 1) * K + wid * 8;
    const ushort_t* bptr  = Bt + (size_t)(colBase + lane) * K + wid * 8;
    const int woff0 = wid * 1024;        // wave-uniform LDS base (+lane*16 by HW)
    const int woff1 = woff0 + 512;

    const int r0 = lane & 15;
    const int kh = lane >> 4;
    const int ardoff = kh * 1024 + (wr * 64 + r0) * 8;
    const int brdoff = kh * 1024 + (wc * 64 + r0) * 8;

    f32x4 zero = {0.f, 0.f, 0.f, 0.f};
    f32x4 acc[4][4];
    #pragma unroll
    for (int i = 0; i < 4; ++i)
        #pragma unroll
        for (int j = 0; j < 4; ++j) acc[i][j] = zero;

    gload_lds16(aptr0, &As[0][woff0]);
    gload_lds16(aptr1, &As[0][woff1]);
    gload_lds16(bptr,  &Bs[0][woff0]);
    gload_lds16(bptr + (size_t)64 * K, &Bs[0][woff1]);
    __syncthreads();

    const ushort_t* rdA = As[0]; const ushort_t* rdB = Bs[0];
    ushort_t*       stA = As[1]; ushort_t*       stB = Bs[1];

    const int nt = K >> 5;
    for (int t = 0; t < nt; ++t) {
        const int kt = (t + 1) << 5;
        if (kt < K) {
            gload_lds16(aptr0 + kt, stA + woff0);
            gload_lds16(aptr1 + kt, stA + woff1);
            gload_lds16(bptr + kt,  stB + woff0);
            gload_lds16(bptr + (size_t)64 * K + kt, stB + woff1);
        }

        bf16x8 af[4], bfr[4];
        #pragma unroll
        for (int fi = 0; fi < 4; ++fi) af[fi] = *(const bf16x8*)(rdA + ardoff + fi * 128);
        #pragma unroll
        for (int fj = 0; fj < 4; ++fj) bfr[fj] = *(const bf16x8*)(rdB + brdoff + fj * 128);
        #pragma unroll
        for (int fi = 0; fi < 4; ++fi)
            #pragma unroll
            for (int fj = 0; fj < 4; ++fj)
                acc[fi][fj] = __builtin_amdgcn_mfma_f32_16x16x32_bf16(
                    af[fi], bfr[fj], acc[fi][fj], 0, 0, 0);

        __syncthreads();
        const ushort_t* tA = rdA; rdA = stA; stA = (ushort_t*)tA;
        const ushort_t* tB = rdB; rdB = stB; stB = (ushort_t*)tB;
    }

    #pragma unroll
    for (int fi = 0; fi < 4; ++fi) {
        int row0 = rowBase + wr * 64 + fi * 16 + kh * 4;
        #pragma unroll
        for (int i = 0; i < 4; ++i) {
            int row = row0 + i;
            if (row < M) {
                #pragma unroll
                for (int fj = 0; fj < 4; ++fj)
                    Cb[(size_t)row * N + colBase + wc * 64 + fj * 16 + r0] = f2b(acc[fi][fj][i]);
            }
        }
    }
}

// ---------- per-node attention halves, layer 1 (bf16 h1) ----------
__global__ __launch_bounds__(256) void alpha1_kernel(const ushort_t* __restrict__ h1b,
                                                     const float* __restrict__ asrc,
                                                     const float* __restrict__ adst,
                                                     float* __restrict__ out_s,
                                                     float* __restrict__ out_d)
{
    int n = blockIdx.x;
    int t = threadIdx.x;
    float h = bf2f(h1b[(size_t)n * C1 + t]);
    float s = h * asrc[t];
    float d = h * adst[t];
    #pragma unroll
    for (int off = 32; off > 0; off >>= 1) {
        s += __shfl_down(s, off);
        d += __shfl_down(d, off);
    }
    if ((t & 63) == 0) {
        out_s[n * HEADS + (t >> 6)] = s;
        out_d[n * HEADS + (t >> 6)] = d;
    }
}

// ---------- per-node attention halves, layer 2 (bf16 h2) ----------
__global__ __launch_bounds__(64) void alpha2_kernel(const ushort_t* __restrict__ h2b,
                                                    const float* __restrict__ asrc,
                                                    const float* __restrict__ adst,
                                                    float* __restrict__ out_s,
                                                    float* __restrict__ out_d)
{
    int n = blockIdx.x;
    int t = threadIdx.x;
    float a = bf2f(h2b[(size_t)n * C2 + t]);
    float b = bf2f(h2b[(size_t)n * C2 + t + 64]);
    float s = a * asrc[t] + b * asrc[t + 64];
    float d = a * adst[t] + b * adst[t + 64];
    #pragma unroll
    for (int off = 32; off > 0; off >>= 1) {
        s += __shfl_down(s, off);
        d += __shfl_down(d, off);
    }
    if (t == 0) { out_s[n] = s; out_d[n] = d; }
}

// ---------- CSR build ----------
__global__ __launch_bounds__(256) void deg_kernel(const int* __restrict__ ei,
                                                  int* __restrict__ deg)
{
    int e = blockIdx.x * blockDim.x + threadIdx.x;
    if (e >= ETOT) return;
    int s, d; edge_sd(ei, e, s, d);
    atomicAdd(&deg[d], 1);
}

// 4 elems/thread + wave shfl scan.
#define SCAN_T 1024
__global__ __launch_bounds__(SCAN_T) void scan_kernel(const int* __restrict__ deg,
                                                      int* __restrict__ rowptr)
{
    __shared__ int wsum[16];
    __shared__ int chunk_tot;
    __shared__ int carry_s;
    const int t = threadIdx.x, lane = t & 63, w = t >> 6;
    if (t == 0) carry_s = 0;
    __syncthreads();
    for (int base = 0; base < NNODES; base += SCAN_T * 4) {
        int idx = base + t * 4;
        int v0 = (idx + 0 < NNODES) ? deg[idx + 0] : 0;
        int v1 = (idx + 1 < NNODES) ? deg[idx + 1] : 0;
        int v2 = (idx + 2 < NNODES) ? deg[idx + 2] : 0;
        int v3 = (idx + 3 < NNODES) ? deg[idx + 3] : 0;
        int p0 = v0, p1 = p0 + v1, p2 = p1 + v2, p3 = p2 + v3;
        int incl = p3;
        #pragma unroll
        for (int off = 1; off < 64; off <<= 1) {
            int nb = __shfl_up(incl, off);
            if (lane >= off) incl += nb;
        }
        if (lane == 63) wsum[w] = incl;
        __syncthreads();
        if (w == 0 && lane < 16) {
            int ws = wsum[lane];
            int wincl = ws;
            #pragma unroll
            for (int off = 1; off < 16; off <<= 1) {
                int nb = __shfl_up(wincl, off);
                if (lane >= off) wincl += nb;
            }
            wsum[lane] = wincl - ws;            // exclusive
            if (lane == 15) chunk_tot = wincl;
        }
        __syncthreads();
        int carry = carry_s;
        int basev = carry + wsum[w] + (incl - p3);
        if (idx + 0 < NNODES) rowptr[idx + 0] = basev;
        if (idx + 1 < NNODES) rowptr[idx + 1] = basev + p0;
        if (idx + 2 < NNODES) rowptr[idx + 2] = basev + p1;
        if (idx + 3 < NNODES) rowptr[idx + 3] = basev + p2;
        __syncthreads();
        if (t == 0) carry_s = carry + chunk_tot;
        __syncthreads();
    }
    if (threadIdx.x == 0) rowptr[NNODES] = carry_s;
}

__global__ __launch_bounds__(256) void scatter_kernel(const int* __restrict__ ei,
                                                      int* __restrict__ cursor,
                                                      int* __restrict__ srcs)
{
    int e = blockIdx.x * blockDim.x + threadIdx.x;
    if (e >= ETOT) return;
    int s, d; edge_sd(ei, e, s, d);
    int pos = atomicAdd(&cursor[d], 1);
    srcs[pos] = s;
}

// ---------- per-edge normalized attention weights, layer 1 (4 heads) ----------
__global__ __launch_bounds__(256) void weights1_kernel(const int* __restrict__ rowptr,
                                                       const int* __restrict__ srcs,
                                                       const float4* __restrict__ as1,
                                                       const float4* __restrict__ ad1,
                                                       float4* __restrict__ wbuf)
{
    int d = blockIdx.x * 4 + (threadIdx.x >> 6);
    if (d >= NNODES) return;
    int lane = threadIdx.x & 63;
    int beg = rowptr[d], end = rowptr[d + 1];
    float4 adv = ad1[d];
    float m0 = -INFINITY, m1 = -INFINITY, m2 = -INFINITY, m3 = -INFINITY;
    for (int i = beg + lane; i < end; i += 64) {
        int s = srcs[i];
        float4 av = as1[s];
        m0 = fmaxf(m0, lrelu(av.x + adv.x));
        m1 = fmaxf(m1, lrelu(av.y + adv.y));
        m2 = fmaxf(m2, lrelu(av.z + adv.z));
        m3 = fmaxf(m3, lrelu(av.w + adv.w));
    }
    #pragma unroll
    for (int off = 32; off > 0; off >>= 1) {
        m0 = fmaxf(m0, __shfl_xor(m0, off));
        m1 = fmaxf(m1, __shfl_xor(m1, off));
        m2 = fmaxf(m2, __shfl_xor(m2, off));
        m3 = fmaxf(m3, __shfl_xor(m3, off));
    }
    float s0 = 0.f, s1 = 0.f, s2 = 0.f, s3 = 0.f;
    for (int i = beg + lane; i < end; i += 64) {
        int s = srcs[i];
        float4 av = as1[s];
        float w0 = expf(lrelu(av.x + adv.x) - m0);
        float w1 = expf(lrelu(av.y + adv.y) - m1);
        float w2 = expf(lrelu(av.z + adv.z) - m2);
        float w3 = expf(lrelu(av.w + adv.w) - m3);
        wbuf[i] = make_float4(w0, w1, w2, w3);
        s0 += w0; s1 += w1; s2 += w2; s3 += w3;
    }
    #pragma unroll
    for (int off = 32; off > 0; off >>= 1) {
        s0 += __shfl_xor(s0, off);
        s1 += __shfl_xor(s1, off);
        s2 += __shfl_xor(s2, off);
        s3 += __shfl_xor(s3, off);
    }
    float i0 = 1.f / (s0 + 1e-16f), i1 = 1.f / (s1 + 1e-16f);
    float i2 = 1.f / (s2 + 1e-16f), i3 = 1.f / (s3 + 1e-16f);
    for (int i = beg + lane; i < end; i += 64) {
        float4 wv = wbuf[i];
        wbuf[i] = make_float4(wv.x * i0, wv.y * i1, wv.z * i2, wv.w * i3);
    }
}

// ---------- per-edge normalized attention weights, layer 2 (1 head) ----------
__global__ __launch_bounds__(256) void weights2_kernel(const int* __restrict__ rowptr,
                                                       const int* __restrict__ srcs,
                                                       const float* __restrict__ as2,
                                                       const float* __restrict__ ad2,
                                                       float* __restrict__ wbuf)
{
    int d = blockIdx.x * 4 + (threadIdx.x >> 6);
    if (d >= NNODES) return;
    int lane = threadIdx.x & 63;
    int beg = rowptr[d], end = rowptr[d + 1];
    float adv = ad2[d];
    float m = -INFINITY;
    for (int i = beg + lane; i < end; i += 64)
        m = fmaxf(m, lrelu(as2[srcs[i]] + adv));
    #pragma unroll
    for (int off = 32; off > 0; off >>= 1) m = fmaxf(m, __shfl_xor(m, off));
    float sm = 0.f;
    for (int i = beg + lane; i < end; i += 64) {
        float w = expf(lrelu(as2[srcs[i]] + adv) - m);
        wbuf[i] = w;
        sm += w;
    }
    #pragma unroll
    for (int off = 32; off > 0; off >>= 1) sm += __shfl_xor(sm, off);
    float inv = 1.f / (sm + 1e-16f);
    for (int i = beg + lane; i < end; i += 64) wbuf[i] *= inv;
}

// ---------- layer-1 aggregation: pure weighted gather (+bias+ELU), bf16 in/out ----------
__global__ __launch_bounds__(256) void aggr1_csr(const int* __restrict__ rowptr,
                                                 const int* __restrict__ srcs,
                                                 const ushort_t* __restrict__ h1b,
                                                 const float* __restrict__ wbuf,
                                                 const float* __restrict__ b1,
                                                 ushort_t* __restrict__ out)
{
    int d = blockIdx.x;
    int t = threadIdx.x;
    int head = t >> 6;
    int beg = rowptr[d], end = rowptr[d + 1];
    float acc = 0.f;
    int i = beg;
    for (; i + 1 < end; i += 2) {
        int s0 = srcs[i], s1 = srcs[i + 1];
        float a0 = wbuf[i * 4 + head], a1 = wbuf[i * 4 + 4 + head];
        float v0 = bf2f(h1b[(size_t)s0 * C1 + t]);
        float v1 = bf2f(h1b[(size_t)s1 * C1 + t]);
        acc = fmaf(a0, v0, acc);
        acc = fmaf(a1, v1, acc);
    }
    if (i < end) {
        int s0 = srcs[i];
        acc = fmaf(wbuf[i * 4 + head], bf2f(h1b[(size_t)s0 * C1 + t]), acc);
    }
    float o = acc + b1[t];
    out[(size_t)d * C1 + t] = f2b(o > 0.f ? o : (expf(o) - 1.f));
}

// ---------- layer-2 aggregation (+bias+L2 normalize), bf16 in, f32 out ----------
__global__ __launch_bounds__(128) void aggr2_csr(const int* __restrict__ rowptr,
                                                 const int* __restrict__ srcs,
                                                 const ushort_t* __restrict__ h2b,
                                                 const float* __restrict__ wbuf,
                                                 const float* __restrict__ b2,
                                                 float* __restrict__ out)
{
    int d = blockIdx.x;
    int t = threadIdx.x;
    int beg = rowptr[d], end = rowptr[d + 1];
    float acc = 0.f;
    int i = beg;
    for (; i + 1 < end; i += 2) {
        int s0 = srcs[i], s1 = srcs[i + 1];
        float a0 = wbuf[i], a1 = wbuf[i + 1];
        float v0 = bf2f(h2b[(size_t)s0 * C2 + t]);
        float v1 = bf2f(h2b[(size_t)s1 * C2 + t]);
        acc = fmaf(a0, v0, acc);
        acc = fmaf(a1, v1, acc);
    }
    if (i < end) acc = fmaf(wbuf[i], bf2f(h2b[(size_t)srcs[i] * C2 + t]), acc);
    float o = acc + b2[t];
    __shared__ float red[2];
    float sq = o * o;
    #pragma unroll
    for (int off = 32; off > 0; off >>= 1) sq += __shfl_down(sq, off);
    if ((t & 63) == 0) red[t >> 6] = sq;
    __syncthreads();
    float total = red[0] + red[1];
    float inv = 1.0f / fmaxf(sqrtf(total), 1e-12f);
    out[(size_t)d * C2 + t] = o * inv;
}

extern "C" void kernel_launch(void* const* d_in, const int* in_sizes, int n_in,
                              void* d_out, int out_size, void* d_ws, size_t ws_size,
                              hipStream_t stream)
{
    const float* x     = (const float*)d_in[0];
    const int*   ei    = (const int*)d_in[1];
    const float* W1    = (const float*)d_in[2];
    const float* asrc1 = (const float*)d_in[3];
    const float* adst1 = (const float*)d_in[4];
    const float* b1    = (const float*)d_in[5];
    const float* W2    = (const float*)d_in[6];
    const float* asrc2 = (const float*)d_in[7];
    const float* adst2 = (const float*)d_in[8];
    const float* b2    = (const float*)d_in[9];
    float* out = (float*)d_out;

    char* ws = (char*)d_ws;
    size_t off = 0;
    auto alloc = [&](size_t nbytes) {
        void* p = ws + off;
        off += (nbytes + 15) & ~(size_t)15;
        return p;
    };
    ushort_t* h1b    = (ushort_t*)alloc((size_t)NNODES * C1 * 2);   // 25.6 MB
    ushort_t* act1b  = (ushort_t*)alloc((size_t)NNODES * C1 * 2);   // 25.6 MB
    ushort_t* h2b    = (ushort_t*)alloc((size_t)NNODES * C2 * 2);   // 12.8 MB
    ushort_t* W1T    = (ushort_t*)alloc((size_t)C1 * IN_DIM * 2);
    ushort_t* W2T    = (ushort_t*)alloc((size_t)C2 * C1 * 2);
    float*    as1    = (float*)alloc((size_t)NNODES * HEADS * 4);
    float*    ad1    = (float*)alloc((size_t)NNODES * HEADS * 4);
    float*    as2    = (float*)alloc((size_t)NNODES * 4);
    float*    ad2    = (float*)alloc((size_t)NNODES * 4);
    float*    wbuf1  = (float*)alloc((size_t)ETOT * HEADS * 4);     // 13.6 MB
    float*    wbuf2  = (float*)alloc((size_t)ETOT * 4);             // 3.4 MB
    int*      deg    = (int*)alloc((size_t)NNODES * 4);
    int*      rowptr = (int*)alloc((size_t)(NNODES + 1) * 4);
    int*      cursor = (int*)alloc((size_t)(NNODES + 1) * 4);
    int*      srcs   = (int*)alloc((size_t)ETOT * 4);               // 3.4 MB

    const int eb = (ETOT + 255) / 256;
    const int nb4 = (NNODES + 3) / 4;

    // ---- weight prep ----
    wtrans_kernel<<<(IN_DIM * C1 + 255) / 256, 256, 0, stream>>>(W1, W1T, IN_DIM, C1);
    wtrans_kernel<<<(C1 * C2 + 255) / 256, 256, 0, stream>>>(W2, W2T, C1, C2);

    // ---- CSR build ----
    hipMemsetAsync(deg, 0, (size_t)NNODES * 4, stream);
    deg_kernel<<<eb, 256, 0, stream>>>(ei, deg);
    scan_kernel<<<1, SCAN_T, 0, stream>>>(deg, rowptr);
    hipMemcpyAsync(cursor, rowptr, (size_t)(NNODES + 1) * 4, hipMemcpyDeviceToDevice, stream);
    scatter_kernel<<<eb, 256, 0, stream>>>(ei, cursor, srcs);

    // ---- Layer 1 ----
    dim3 g1(C1 / 128, (NNODES + 127) / 128);
    gemm_fb<<<g1, 256, 0, stream>>>(x, W1T, h1b, NNODES, C1, IN_DIM);
    alpha1_kernel<<<NNODES, 256, 0, stream>>>(h1b, asrc1, adst1, as1, ad1);
    weights1_kernel<<<nb4, 256, 0, stream>>>(rowptr, srcs, (const float4*)as1,
                                             (const float4*)ad1, (float4*)wbuf1);
    aggr1_csr<<<NNODES, 256, 0, stream>>>(rowptr, srcs, h1b, wbuf1, b1, act1b);

    // ---- Layer 2 ----
    dim3 g2(C2 / 128, (NNODES + 127) / 128);
    gemm_bb<<<g2, 256, 0, stream>>>(act1b, W2T, h2b, NNODES, C2, C1);
    alpha2_kernel<<<NNODES, 64, 0, stream>>>(h2b, asrc2, adst2, as2, ad2);
    weights2_kernel<<<nb4, 256, 0, stream>>>(rowptr, srcs, as2, ad2, wbuf2);
    aggr2_csr<<<NNODES, 128, 0, stream>>>(rowptr, srcs, h2b, wbuf2, b2, out);
}

// Round 8
// 489.569 us; speedup vs baseline: 1.1020x; 1.1020x over previous
//
#include <hip/hip_runtime.h>
#include <math.h>

#define NNODES 50000
#define E0 800000
#define ETOT 850000
#define IN_DIM 1024
#define HEADS 4
#define C1 256      // HEADS*HID
#define C2 128      // OUT_DIM
#define NEG_SLOPE 0.2f

typedef short bf16x8 __attribute__((ext_vector_type(8)));
typedef float f32x4 __attribute__((ext_vector_type(4)));
typedef unsigned short ushort_t;

// ---------- helpers ----------
// NOTE: harness delivers integer inputs as int32 (verified round 1: int* passed,
// long long* faulted). Do NOT read edge_index as int64.
__device__ __forceinline__ void edge_sd(const int* __restrict__ ei, int e, int& s, int& d) {
    if (e < E0) { s = ei[e]; d = ei[E0 + e]; }
    else        { s = e - E0; d = s; }
}

__device__ __forceinline__ ushort_t f2b(float f) {   // f32 -> bf16 RNE
    unsigned u = __float_as_uint(f);
    return (ushort_t)((u + 0x7fffu + ((u >> 16) & 1u)) >> 16);
}
__device__ __forceinline__ float bf2f(ushort_t u) {
    return __uint_as_float((unsigned)u << 16);
}
__device__ __forceinline__ float lrelu(float v) { return v > 0.f ? v : NEG_SLOPE * v; }

__device__ __forceinline__ void gload_lds16(const void* g, void* l) {
    __builtin_amdgcn_global_load_lds(
        (const __attribute__((address_space(1))) unsigned int*)g,
        (__attribute__((address_space(3))) unsigned int*)l, 16, 0, 0);
}

// ---------- weight transpose + bf16 cast: W[K][N] f32 -> WT[N][K] bf16 ----------
__global__ __launch_bounds__(256) void wtrans_kernel(const float* __restrict__ W,
                                                     ushort_t* __restrict__ WT,
                                                     int K, int N)
{
    int idx = blockIdx.x * 256 + threadIdx.x;
    if (idx >= K * N) return;
    int k = idx / N, n = idx % N;
    WT[(size_t)n * K + k] = f2b(W[idx]);
}

// ---------- MFMA GEMM (A f32, cast in regs): Cb bf16 = A[M][K] @ Bt[N][K] ----------
// 64x128 tile, BK=32, 4 waves (2x2, each 32x64), double-buffered.
// LDS per buffer: A [kchunk(4)][64][8], B [kchunk(4)][128][8] bf16.
__global__ __launch_bounds__(256, 6) void gemm_fb(const float* __restrict__ A,
                                                  const ushort_t* __restrict__ Bt,
                                                  ushort_t* __restrict__ Cb,
                                                  int M, int N, int K)
{
    __shared__ __align__(16) ushort_t As[2][4 * 64 * 8];    // 2 x 4 KB
    __shared__ __align__(16) ushort_t Bs[2][4 * 128 * 8];   // 2 x 8 KB

    const int tid  = threadIdx.x;
    const int lane = tid & 63;
    const int wid  = tid >> 6;
    const int wr   = wid >> 1, wc = wid & 1;
    const int rowBase = blockIdx.y * 64;
    const int colBase = blockIdx.x * 128;

    // A staging (reg path): thread t covers row=t>>2, kchunk=t&3 (8 f32)
    const int arow = tid >> 2;
    const int akc  = tid & 3;
    const int aGRow = min(rowBase + arow, M - 1);
    const float* aptr = A + (size_t)aGRow * K + akc * 8;
    const int awoff = akc * 512 + arow * 8;

    // B staging via global_load_lds: wave w stages kchunk plane w, halves c=0/1
    const ushort_t* bptr = Bt + (size_t)(colBase + lane) * K + wid * 8;
    const int bwoff0 = wid * 1024;       // wave-uniform LDS base (+lane*16 by HW)
    const int bwoff1 = bwoff0 + 512;

    const int r0 = lane & 15;
    const int kh = lane >> 4;
    const int ardoff = kh * 512 + (wr * 32 + r0) * 8;
    const int brdoff = kh * 1024 + (wc * 64 + r0) * 8;

    f32x4 zero = {0.f, 0.f, 0.f, 0.f};
    f32x4 acc[2][4];
    #pragma unroll
    for (int i = 0; i < 2; ++i)
        #pragma unroll
        for (int j = 0; j < 4; ++j) acc[i][j] = zero;

    // ---- prologue: stage tile 0 into buffer 0 ----
    {
        float4 f0 = *(const float4*)(aptr + 0);
        float4 f1 = *(const float4*)(aptr + 4);
        bf16x8 p0;
        p0[0] = f2b(f0.x); p0[1] = f2b(f0.y); p0[2] = f2b(f0.z); p0[3] = f2b(f0.w);
        p0[4] = f2b(f1.x); p0[5] = f2b(f1.y); p0[6] = f2b(f1.z); p0[7] = f2b(f1.w);
        *(bf16x8*)&As[0][awoff] = p0;
        gload_lds16(bptr, &Bs[0][bwoff0]);
        gload_lds16(bptr + (size_t)64 * K, &Bs[0][bwoff1]);
    }
    __syncthreads();

    const ushort_t* rdA = As[0]; const ushort_t* rdB = Bs[0];
    ushort_t*       stA = As[1]; ushort_t*       stB = Bs[1];

    const int nt = K >> 5;
    for (int t = 0; t < nt; ++t) {
        const int kt = (t + 1) << 5;
        const bool has_next = kt < K;
        float4 f0, f1;
        if (has_next) {
            gload_lds16(bptr + kt, stB + bwoff0);
            gload_lds16(bptr + (size_t)64 * K + kt, stB + bwoff1);
            f0 = *(const float4*)(aptr + kt + 0);
            f1 = *(const float4*)(aptr + kt + 4);
        }

        bf16x8 af[2], bfr[4];
        #pragma unroll
        for (int fi = 0; fi < 2; ++fi) af[fi] = *(const bf16x8*)(rdA + ardoff + fi * 128);
        #pragma unroll
        for (int fj = 0; fj < 4; ++fj) bfr[fj] = *(const bf16x8*)(rdB + brdoff + fj * 128);
        #pragma unroll
        for (int fi = 0; fi < 2; ++fi)
            #pragma unroll
            for (int fj = 0; fj < 4; ++fj)
                acc[fi][fj] = __builtin_amdgcn_mfma_f32_16x16x32_bf16(
                    af[fi], bfr[fj], acc[fi][fj], 0, 0, 0);

        if (has_next) {
            bf16x8 p0;
            p0[0] = f2b(f0.x); p0[1] = f2b(f0.y); p0[2] = f2b(f0.z); p0[3] = f2b(f0.w);
            p0[4] = f2b(f1.x); p0[5] = f2b(f1.y); p0[6] = f2b(f1.z); p0[7] = f2b(f1.w);
            *(bf16x8*)(stA + awoff) = p0;
        }
        __syncthreads();
        const ushort_t* tA = rdA; rdA = stA; stA = (ushort_t*)tA;
        const ushort_t* tB = rdB; rdB = stB; stB = (ushort_t*)tB;
    }

    // C/D layout (m89-verified): col = lane&15, row = (lane>>4)*4 + reg
    #pragma unroll
    for (int fi = 0; fi < 2; ++fi) {
        int row0 = rowBase + wr * 32 + fi * 16 + kh * 4;
        #pragma unroll
        for (int i = 0; i < 4; ++i) {
            int row = row0 + i;
            if (row < M) {
                #pragma unroll
                for (int fj = 0; fj < 4; ++fj)
                    Cb[(size_t)row * N + colBase + wc * 64 + fj * 16 + r0] = f2b(acc[fi][fj][i]);
            }
        }
    }
}

// ---------- MFMA GEMM (A bf16 direct): same 64x128 double-buffered pipeline ----------
__global__ __launch_bounds__(256, 6) void gemm_bb(const ushort_t* __restrict__ Ab,
                                                  const ushort_t* __restrict__ Bt,
                                                  ushort_t* __restrict__ Cb,
                                                  int M, int N, int K)
{
    __shared__ __align__(16) ushort_t As[2][4 * 64 * 8];
    __shared__ __align__(16) ushort_t Bs[2][4 * 128 * 8];

    const int tid  = threadIdx.x;
    const int lane = tid & 63;
    const int wid  = tid >> 6;
    const int wr   = wid >> 1, wc = wid & 1;
    const int rowBase = blockIdx.y * 64;
    const int colBase = blockIdx.x * 128;

    // wave w stages: A kchunk w (64 rows, one gload), B kchunk w (two gloads)
    const ushort_t* aptr = Ab + (size_t)min(rowBase + lane, M - 1) * K + wid * 8;
    const ushort_t* bptr = Bt + (size_t)(colBase + lane) * K + wid * 8;
    const int awoff  = wid * 512;
    const int bwoff0 = wid * 1024;
    const int bwoff1 = bwoff0 + 512;

    const int r0 = lane & 15;
    const int kh = lane >> 4;
    const int ardoff = kh * 512 + (wr * 32 + r0) * 8;
    const int brdoff = kh * 1024 + (wc * 64 + r0) * 8;

    f32x4 zero = {0.f, 0.f, 0.f, 0.f};
    f32x4 acc[2][4];
    #pragma unroll
    for (int i = 0; i < 2; ++i)
        #pragma unroll
        for (int j = 0; j < 4; ++j) acc[i][j] = zero;

    gload_lds16(aptr, &As[0][awoff]);
    gload_lds16(bptr, &Bs[0][bwoff0]);
    gload_lds16(bptr + (size_t)64 * K, &Bs[0][bwoff1]);
    __syncthreads();

    const ushort_t* rdA = As[0]; const ushort_t* rdB = Bs[0];
    ushort_t*       stA = As[1]; ushort_t*       stB = Bs[1];

    const int nt = K >> 5;
    for (int t = 0; t < nt; ++t) {
        const int kt = (t + 1) << 5;
        if (kt < K) {
            gload_lds16(aptr + kt, stA + awoff);
            gload_lds16(bptr + kt, stB + bwoff0);
            gload_lds16(bptr + (size_t)64 * K + kt, stB + bwoff1);
        }

        bf16x8 af[2], bfr[4];
        #pragma unroll
        for (int fi = 0; fi < 2; ++fi) af[fi] = *(const bf16x8*)(rdA + ardoff + fi * 128);
        #pragma unroll
        for (int fj = 0; fj < 4; ++fj) bfr[fj] = *(const bf16x8*)(rdB + brdoff + fj * 128);
        #pragma unroll
        for (int fi = 0; fi < 2; ++fi)
            #pragma unroll
            for (int fj = 0; fj < 4; ++fj)
                acc[fi][fj] = __builtin_amdgcn_mfma_f32_16x16x32_bf16(
                    af[fi], bfr[fj], acc[fi][fj], 0, 0, 0);

        __syncthreads();
        const ushort_t* tA = rdA; rdA = stA; stA = (ushort_t*)tA;
        const ushort_t* tB = rdB; rdB = stB; stB = (ushort_t*)tB;
    }

    #pragma unroll
    for (int fi = 0; fi < 2; ++fi) {
        int row0 = rowBase + wr * 32 + fi * 16 + kh * 4;
        #pragma unroll
        for (int i = 0; i < 4; ++i) {
            int row = row0 + i;
            if (row < M) {
                #pragma unroll
                for (int fj = 0; fj < 4; ++fj)
                    Cb[(size_t)row * N + colBase + wc * 64 + fj * 16 + r0] = f2b(acc[fi][fj][i]);
            }
        }
    }
}

// ---------- per-node attention halves, layer 1 (bf16 h1) ----------
__global__ __launch_bounds__(256) void alpha1_kernel(const ushort_t* __restrict__ h1b,
                                                     const float* __restrict__ asrc,
                                                     const float* __restrict__ adst,
                                                     float* __restrict__ out_s,
                                                     float* __restrict__ out_d)
{
    int n = blockIdx.x;
    int t = threadIdx.x;
    float h = bf2f(h1b[(size_t)n * C1 + t]);
    float s = h * asrc[t];
    float d = h * adst[t];
    #pragma unroll
    for (int off = 32; off > 0; off >>= 1) {
        s += __shfl_down(s, off);
        d += __shfl_down(d, off);
    }
    if ((t & 63) == 0) {
        out_s[n * HEADS + (t >> 6)] = s;
        out_d[n * HEADS + (t >> 6)] = d;
    }
}

// ---------- per-node attention halves, layer 2 (bf16 h2) ----------
__global__ __launch_bounds__(64) void alpha2_kernel(const ushort_t* __restrict__ h2b,
                                                    const float* __restrict__ asrc,
                                                    const float* __restrict__ adst,
                                                    float* __restrict__ out_s,
                                                    float* __restrict__ out_d)
{
    int n = blockIdx.x;
    int t = threadIdx.x;
    float a = bf2f(h2b[(size_t)n * C2 + t]);
    float b = bf2f(h2b[(size_t)n * C2 + t + 64]);
    float s = a * asrc[t] + b * asrc[t + 64];
    float d = a * adst[t] + b * adst[t + 64];
    #pragma unroll
    for (int off = 32; off > 0; off >>= 1) {
        s += __shfl_down(s, off);
        d += __shfl_down(d, off);
    }
    if (t == 0) { out_s[n] = s; out_d[n] = d; }
}

// ---------- CSR build ----------
__global__ __launch_bounds__(256) void deg_kernel(const int* __restrict__ ei,
                                                  int* __restrict__ deg)
{
    int e = blockIdx.x * blockDim.x + threadIdx.x;
    if (e >= ETOT) return;
    int s, d; edge_sd(ei, e, s, d);
    atomicAdd(&deg[d], 1);
}

// 4 elems/thread + wave shfl scan.
#define SCAN_T 1024
__global__ __launch_bounds__(SCAN_T) void scan_kernel(const int* __restrict__ deg,
                                                      int* __restrict__ rowptr)
{
    __shared__ int wsum[16];
    __shared__ int chunk_tot;
    __shared__ int carry_s;
    const int t = threadIdx.x, lane = t & 63, w = t >> 6;
    if (t == 0) carry_s = 0;
    __syncthreads();
    for (int base = 0; base < NNODES; base += SCAN_T * 4) {
        int idx = base + t * 4;
        int v0 = (idx + 0 < NNODES) ? deg[idx + 0] : 0;
        int v1 = (idx + 1 < NNODES) ? deg[idx + 1] : 0;
        int v2 = (idx + 2 < NNODES) ? deg[idx + 2] : 0;
        int v3 = (idx + 3 < NNODES) ? deg[idx + 3] : 0;
        int p0 = v0, p1 = p0 + v1, p2 = p1 + v2, p3 = p2 + v3;
        int incl = p3;
        #pragma unroll
        for (int off = 1; off < 64; off <<= 1) {
            int nb = __shfl_up(incl, off);
            if (lane >= off) incl += nb;
        }
        if (lane == 63) wsum[w] = incl;
        __syncthreads();
        if (w == 0 && lane < 16) {
            int ws = wsum[lane];
            int wincl = ws;
            #pragma unroll
            for (int off = 1; off < 16; off <<= 1) {
                int nb = __shfl_up(wincl, off);
                if (lane >= off) wincl += nb;
            }
            wsum[lane] = wincl - ws;            // exclusive
            if (lane == 15) chunk_tot = wincl;
        }
        __syncthreads();
        int carry = carry_s;
        int basev = carry + wsum[w] + (incl - p3);
        if (idx + 0 < NNODES) rowptr[idx + 0] = basev;
        if (idx + 1 < NNODES) rowptr[idx + 1] = basev + p0;
        if (idx + 2 < NNODES) rowptr[idx + 2] = basev + p1;
        if (idx + 3 < NNODES) rowptr[idx + 3] = basev + p2;
        __syncthreads();
        if (t == 0) carry_s = carry + chunk_tot;
        __syncthreads();
    }
    if (threadIdx.x == 0) rowptr[NNODES] = carry_s;
}

__global__ __launch_bounds__(256) void scatter_kernel(const int* __restrict__ ei,
                                                      int* __restrict__ cursor,
                                                      int* __restrict__ srcs)
{
    int e = blockIdx.x * blockDim.x + threadIdx.x;
    if (e >= ETOT) return;
    int s, d; edge_sd(ei, e, s, d);
    int pos = atomicAdd(&cursor[d], 1);
    srcs[pos] = s;
}

// ---------- per-edge normalized attention weights, layer 1 (4 heads) ----------
__global__ __launch_bounds__(256) void weights1_kernel(const int* __restrict__ rowptr,
                                                       const int* __restrict__ srcs,
                                                       const float4* __restrict__ as1,
                                                       const float4* __restrict__ ad1,
                                                       float4* __restrict__ wbuf)
{
    int d = blockIdx.x * 4 + (threadIdx.x >> 6);
    if (d >= NNODES) return;
    int lane = threadIdx.x & 63;
    int beg = rowptr[d], end = rowptr[d + 1];
    float4 adv = ad1[d];
    float m0 = -INFINITY, m1 = -INFINITY, m2 = -INFINITY, m3 = -INFINITY;
    for (int i = beg + lane; i < end; i += 64) {
        int s = srcs[i];
        float4 av = as1[s];
        m0 = fmaxf(m0, lrelu(av.x + adv.x));
        m1 = fmaxf(m1, lrelu(av.y + adv.y));
        m2 = fmaxf(m2, lrelu(av.z + adv.z));
        m3 = fmaxf(m3, lrelu(av.w + adv.w));
    }
    #pragma unroll
    for (int off = 32; off > 0; off >>= 1) {
        m0 = fmaxf(m0, __shfl_xor(m0, off));
        m1 = fmaxf(m1, __shfl_xor(m1, off));
        m2 = fmaxf(m2, __shfl_xor(m2, off));
        m3 = fmaxf(m3, __shfl_xor(m3, off));
    }
    float s0 = 0.f, s1 = 0.f, s2 = 0.f, s3 = 0.f;
    for (int i = beg + lane; i < end; i += 64) {
        int s = srcs[i];
        float4 av = as1[s];
        float w0 = expf(lrelu(av.x + adv.x) - m0);
        float w1 = expf(lrelu(av.y + adv.y) - m1);
        float w2 = expf(lrelu(av.z + adv.z) - m2);
        float w3 = expf(lrelu(av.w + adv.w) - m3);
        wbuf[i] = make_float4(w0, w1, w2, w3);
        s0 += w0; s1 += w1; s2 += w2; s3 += w3;
    }
    #pragma unroll
    for (int off = 32; off > 0; off >>= 1) {
        s0 += __shfl_xor(s0, off);
        s1 += __shfl_xor(s1, off);
        s2 += __shfl_xor(s2, off);
        s3 += __shfl_xor(s3, off);
    }
    float i0 = 1.f / (s0 + 1e-16f), i1 = 1.f / (s1 + 1e-16f);
    float i2 = 1.f / (s2 + 1e-16f), i3 = 1.f / (s3 + 1e-16f);
    for (int i = beg + lane; i < end; i += 64) {
        float4 wv = wbuf[i];
        wbuf[i] = make_float4(wv.x * i0, wv.y * i1, wv.z * i2, wv.w * i3);
    }
}

// ---------- per-edge normalized attention weights, layer 2 (1 head) ----------
__global__ __launch_bounds__(256) void weights2_kernel(const int* __restrict__ rowptr,
                                                       const int* __restrict__ srcs,
                                                       const float* __restrict__ as2,
                                                       const float* __restrict__ ad2,
                                                       float* __restrict__ wbuf)
{
    int d = blockIdx.x * 4 + (threadIdx.x >> 6);
    if (d >= NNODES) return;
    int lane = threadIdx.x & 63;
    int beg = rowptr[d], end = rowptr[d + 1];
    float adv = ad2[d];
    float m = -INFINITY;
    for (int i = beg + lane; i < end; i += 64)
        m = fmaxf(m, lrelu(as2[srcs[i]] + adv));
    #pragma unroll
    for (int off = 32; off > 0; off >>= 1) m = fmaxf(m, __shfl_xor(m, off));
    float sm = 0.f;
    for (int i = beg + lane; i < end; i += 64) {
        float w = expf(lrelu(as2[srcs[i]] + adv) - m);
        wbuf[i] = w;
        sm += w;
    }
    #pragma unroll
    for (int off = 32; off > 0; off >>= 1) sm += __shfl_xor(sm, off);
    float inv = 1.f / (sm + 1e-16f);
    for (int i = beg + lane; i < end; i += 64) wbuf[i] *= inv;
}

// ---------- layer-1 aggregation: wave per dst, lane = 4 channels (ushort4 loads) ----------
__global__ __launch_bounds__(256) void aggr1_csr(const int* __restrict__ rowptr,
                                                 const int* __restrict__ srcs,
                                                 const ushort_t* __restrict__ h1b,
                                                 const float* __restrict__ wbuf,
                                                 const float* __restrict__ b1,
                                                 ushort_t* __restrict__ out)
{
    int d = blockIdx.x * 4 + (threadIdx.x >> 6);
    if (d >= NNODES) return;
    int lane = threadIdx.x & 63;
    int c0 = lane * 4;                 // channels [c0, c0+4)
    int head = lane >> 4;              // c0>>6
    int beg = rowptr[d], end = rowptr[d + 1];
    float a0 = 0.f, a1 = 0.f, a2 = 0.f, a3 = 0.f;
    int i = beg;
    for (; i + 1 < end; i += 2) {
        int s0 = srcs[i], s1 = srcs[i + 1];
        float w0 = wbuf[i * 4 + head], w1 = wbuf[i * 4 + 4 + head];
        ushort4 v0 = *(const ushort4*)(h1b + (size_t)s0 * C1 + c0);
        ushort4 v1 = *(const ushort4*)(h1b + (size_t)s1 * C1 + c0);
        a0 = fmaf(w0, bf2f(v0.x), a0); a1 = fmaf(w0, bf2f(v0.y), a1);
        a2 = fmaf(w0, bf2f(v0.z), a2); a3 = fmaf(w0, bf2f(v0.w), a3);
        a0 = fmaf(w1, bf2f(v1.x), a0); a1 = fmaf(w1, bf2f(v1.y), a1);
        a2 = fmaf(w1, bf2f(v1.z), a2); a3 = fmaf(w1, bf2f(v1.w), a3);
    }
    if (i < end) {
        int s0 = srcs[i];
        float w0 = wbuf[i * 4 + head];
        ushort4 v0 = *(const ushort4*)(h1b + (size_t)s0 * C1 + c0);
        a0 = fmaf(w0, bf2f(v0.x), a0); a1 = fmaf(w0, bf2f(v0.y), a1);
        a2 = fmaf(w0, bf2f(v0.z), a2); a3 = fmaf(w0, bf2f(v0.w), a3);
    }
    float4 bv = *(const float4*)(b1 + c0);
    float o0 = a0 + bv.x, o1 = a1 + bv.y, o2 = a2 + bv.z, o3 = a3 + bv.w;
    ushort4 r;
    r.x = f2b(o0 > 0.f ? o0 : (expf(o0) - 1.f));
    r.y = f2b(o1 > 0.f ? o1 : (expf(o1) - 1.f));
    r.z = f2b(o2 > 0.f ? o2 : (expf(o2) - 1.f));
    r.w = f2b(o3 > 0.f ? o3 : (expf(o3) - 1.f));
    *(ushort4*)(out + (size_t)d * C1 + c0) = r;
}

// ---------- layer-2 aggregation: wave per dst, lane = 2 channels (+bias+L2 norm) ----------
__global__ __launch_bounds__(256) void aggr2_csr(const int* __restrict__ rowptr,
                                                 const int* __restrict__ srcs,
                                                 const ushort_t* __restrict__ h2b,
                                                 const float* __restrict__ wbuf,
                                                 const float* __restrict__ b2,
                                                 float* __restrict__ out)
{
    int d = blockIdx.x * 4 + (threadIdx.x >> 6);
    if (d >= NNODES) return;
    int lane = threadIdx.x & 63;
    int c0 = lane * 2;
    int beg = rowptr[d], end = rowptr[d + 1];
    float a0 = 0.f, a1 = 0.f;
    int i = beg;
    for (; i + 1 < end; i += 2) {
        int s0 = srcs[i], s1 = srcs[i + 1];
        float w0 = wbuf[i], w1 = wbuf[i + 1];
        ushort2 v0 = *(const ushort2*)(h2b + (size_t)s0 * C2 + c0);
        ushort2 v1 = *(const ushort2*)(h2b + (size_t)s1 * C2 + c0);
        a0 = fmaf(w0, bf2f(v0.x), a0); a1 = fmaf(w0, bf2f(v0.y), a1);
        a0 = fmaf(w1, bf2f(v1.x), a0); a1 = fmaf(w1, bf2f(v1.y), a1);
    }
    if (i < end) {
        float w0 = wbuf[i];
        ushort2 v0 = *(const ushort2*)(h2b + (size_t)srcs[i] * C2 + c0);
        a0 = fmaf(w0, bf2f(v0.x), a0); a1 = fmaf(w0, bf2f(v0.y), a1);
    }
    float2 bv = *(const float2*)(b2 + c0);
    float o0 = a0 + bv.x, o1 = a1 + bv.y;
    float sq = o0 * o0 + o1 * o1;
    #pragma unroll
    for (int off = 32; off > 0; off >>= 1) sq += __shfl_xor(sq, off);
    float inv = 1.0f / fmaxf(sqrtf(sq), 1e-12f);
    float2 r = make_float2(o0 * inv, o1 * inv);
    *(float2*)(out + (size_t)d * C2 + c0) = r;
}

extern "C" void kernel_launch(void* const* d_in, const int* in_sizes, int n_in,
                              void* d_out, int out_size, void* d_ws, size_t ws_size,
                              hipStream_t stream)
{
    const float* x     = (const float*)d_in[0];
    const int*   ei    = (const int*)d_in[1];
    const float* W1    = (const float*)d_in[2];
    const float* asrc1 = (const float*)d_in[3];
    const float* adst1 = (const float*)d_in[4];
    const float* b1    = (const float*)d_in[5];
    const float* W2    = (const float*)d_in[6];
    const float* asrc2 = (const float*)d_in[7];
    const float* adst2 = (const float*)d_in[8];
    const float* b2    = (const float*)d_in[9];
    float* out = (float*)d_out;

    char* ws = (char*)d_ws;
    size_t off = 0;
    auto alloc = [&](size_t nbytes) {
        void* p = ws + off;
        off += (nbytes + 15) & ~(size_t)15;
        return p;
    };
    ushort_t* h1b    = (ushort_t*)alloc((size_t)NNODES * C1 * 2);   // 25.6 MB
    ushort_t* act1b  = (ushort_t*)alloc((size_t)NNODES * C1 * 2);   // 25.6 MB
    ushort_t* h2b    = (ushort_t*)alloc((size_t)NNODES * C2 * 2);   // 12.8 MB
    ushort_t* W1T    = (ushort_t*)alloc((size_t)C1 * IN_DIM * 2);
    ushort_t* W2T    = (ushort_t*)alloc((size_t)C2 * C1 * 2);
    float*    as1    = (float*)alloc((size_t)NNODES * HEADS * 4);
    float*    ad1    = (float*)alloc((size_t)NNODES * HEADS * 4);
    float*    as2    = (float*)alloc((size_t)NNODES * 4);
    float*    ad2    = (float*)alloc((size_t)NNODES * 4);
    float*    wbuf1  = (float*)alloc((size_t)ETOT * HEADS * 4);     // 13.6 MB
    float*    wbuf2  = (float*)alloc((size_t)ETOT * 4);             // 3.4 MB
    int*      deg    = (int*)alloc((size_t)NNODES * 4);
    int*      rowptr = (int*)alloc((size_t)(NNODES + 1) * 4);
    int*      cursor = (int*)alloc((size_t)(NNODES + 1) * 4);
    int*      srcs   = (int*)alloc((size_t)ETOT * 4);               // 3.4 MB

    const int eb = (ETOT + 255) / 256;
    const int nb4 = (NNODES + 3) / 4;

    // ---- weight prep ----
    wtrans_kernel<<<(IN_DIM * C1 + 255) / 256, 256, 0, stream>>>(W1, W1T, IN_DIM, C1);
    wtrans_kernel<<<(C1 * C2 + 255) / 256, 256, 0, stream>>>(W2, W2T, C1, C2);

    // ---- CSR build ----
    hipMemsetAsync(deg, 0, (size_t)NNODES * 4, stream);
    deg_kernel<<<eb, 256, 0, stream>>>(ei, deg);
    scan_kernel<<<1, SCAN_T, 0, stream>>>(deg, rowptr);
    hipMemcpyAsync(cursor, rowptr, (size_t)(NNODES + 1) * 4, hipMemcpyDeviceToDevice, stream);
    scatter_kernel<<<eb, 256, 0, stream>>>(ei, cursor, srcs);

    // ---- Layer 1 ----
    dim3 g1(C1 / 128, (NNODES + 63) / 64);
    gemm_fb<<<g1, 256, 0, stream>>>(x, W1T, h1b, NNODES, C1, IN_DIM);
    alpha1_kernel<<<NNODES, 256, 0, stream>>>(h1b, asrc1, adst1, as1, ad1);
    weights1_kernel<<<nb4, 256, 0, stream>>>(rowptr, srcs, (const float4*)as1,
                                             (const float4*)ad1, (float4*)wbuf1);
    aggr1_csr<<<nb4, 256, 0, stream>>>(rowptr, srcs, h1b, wbuf1, b1, act1b);

    // ---- Layer 2 ----
    dim3 g2(C2 / 128, (NNODES + 63) / 64);
    gemm_bb<<<g2, 256, 0, stream>>>(act1b, W2T, h2b, NNODES, C2, C1);
    alpha2_kernel<<<NNODES, 64, 0, stream>>>(h2b, asrc2, adst2, as2, ad2);
    weights2_kernel<<<nb4, 256, 0, stream>>>(rowptr, srcs, as2, ad2, wbuf2);
    aggr2_csr<<<nb4, 256, 0, stream>>>(rowptr, srcs, h2b, wbuf2, b2, out);
}